// Round 1
// baseline (3466.576 us; speedup 1.0000x reference)
//
#include <hip/hip_runtime.h>
#include <hip/hip_bf16.h>

typedef __bf16  bf16x8_t __attribute__((ext_vector_type(8)));
typedef float   f32x4_t  __attribute__((ext_vector_type(4)));

#define N_COL 512   // all GEMMs have 512 output columns
#define NB    4     // N_COL / 128

__device__ __forceinline__ ushort f2bf(float f) {
    unsigned u = __float_as_uint(f);
    unsigned r = (u + 0x7FFFu + ((u >> 16) & 1u)) >> 16;   // RNE
    return (ushort)r;
}

// EPI: 0 = plain f32 store, 1 = scale by softmax(alpha)[m0>=Asplit], 2 = relu(max(acc,aux)+bias)
template <int EPI>
__global__ void gemm_bf16_k(const float* __restrict__ A0, const float* __restrict__ A1,
                            int Asplit, int lda,
                            const float* __restrict__ B, float* __restrict__ C,
                            int M, int K,
                            const float* __restrict__ alphap,
                            const float* __restrict__ bias,
                            const float* __restrict__ aux) {
    __shared__ __attribute__((aligned(16))) ushort As[128 * 64];
    __shared__ __attribute__((aligned(16))) ushort Bs[128 * 64];

    const int tid  = threadIdx.x;
    const int wave = tid >> 6;
    const int lane = tid & 63;

    // XCD-aware swizzle (grid % 8 == 0 for all our launches)
    int bid = blockIdx.x;
    int nwg = gridDim.x;
    if ((nwg & 7) == 0) {
        int per = nwg >> 3;
        bid = (bid & 7) * per + (bid >> 3);
    }
    const int bm = bid / NB;
    const int bn = bid % NB;
    const int m0 = bm * 128;
    const int n0 = bn * 128;

    // A source select (stacked-A case for t = [s1;s3] @ pre)
    const float* Ap = A0;
    int mrow = m0;
    if (m0 >= Asplit) { Ap = A1; mrow = m0 - Asplit; }

    // staging thread decomposition
    const int tr = tid >> 4;   // 0..15  (A row group)
    const int tc = tid & 15;   // 0..15  (A col group: 4 floats)
    const int nn = tid >> 1;   // 0..127 (B column handled by this thread)
    const int c2 = tid & 1;    // 0/1    (B k-chunk phase)

    f32x4_t ra[8];
    float   rb[8][4];

    const int KT = K >> 6;   // K / 64

    auto load_tile = [&](int t) {
        const float* Ab = Ap + (size_t)(mrow + tr) * lda + (size_t)t * 64 + tc * 4;
#pragma unroll
        for (int i = 0; i < 8; ++i)
            ra[i] = *(const f32x4_t*)(Ab + (size_t)i * 16 * lda);
        const float* Bb = B + (size_t)(t * 64 + c2 * 4) * N_COL + n0 + nn;
#pragma unroll
        for (int i = 0; i < 8; ++i)
#pragma unroll
            for (int j = 0; j < 4; ++j)
                rb[i][j] = Bb[(size_t)(i * 8 + j) * N_COL];
    };

    auto stage = [&]() {
#pragma unroll
        for (int i = 0; i < 8; ++i) {
            int r = i * 16 + tr;
            ushort4 p;
            p.x = f2bf(ra[i][0]); p.y = f2bf(ra[i][1]);
            p.z = f2bf(ra[i][2]); p.w = f2bf(ra[i][3]);
            *(ushort4*)&As[r * 64 + ((tc * 4) ^ ((r & 7) << 3))] = p;
        }
#pragma unroll
        for (int i = 0; i < 8; ++i) {
            int kb = c2 * 4 + i * 8;
            ushort4 p;
            p.x = f2bf(rb[i][0]); p.y = f2bf(rb[i][1]);
            p.z = f2bf(rb[i][2]); p.w = f2bf(rb[i][3]);
            *(ushort4*)&Bs[nn * 64 + (kb ^ ((nn & 7) << 3))] = p;
        }
    };

    // wave tile: 64x64, 4x4 fragments of 16x16
    const int wm  = (wave >> 1) * 64;
    const int wn  = (wave & 1) * 64;
    const int l15 = lane & 15;
    const int lk  = (lane >> 4) << 3;   // k-group offset 0/8/16/24

    f32x4_t acc[4][4];
#pragma unroll
    for (int i = 0; i < 4; ++i)
#pragma unroll
        for (int j = 0; j < 4; ++j)
            acc[i][j] = (f32x4_t)0.f;

    load_tile(0);
    for (int t = 0; t < KT; ++t) {
        __syncthreads();
        stage();
        __syncthreads();
        if (t + 1 < KT) load_tile(t + 1);   // prefetch next tile; latency hides under MFMA
#pragma unroll
        for (int ks = 0; ks < 2; ++ks) {
            bf16x8_t af[4], bv[4];
            int kc = ks * 32 + lk;
#pragma unroll
            for (int f = 0; f < 4; ++f) {
                int r  = wm + f * 16 + l15;
                af[f] = *(const bf16x8_t*)&As[r * 64 + (kc ^ ((r & 7) << 3))];
                int n2 = wn + f * 16 + l15;
                bv[f] = *(const bf16x8_t*)&Bs[n2 * 64 + (kc ^ ((n2 & 7) << 3))];
            }
#pragma unroll
            for (int i = 0; i < 4; ++i)
#pragma unroll
                for (int j = 0; j < 4; ++j)
                    acc[i][j] = __builtin_amdgcn_mfma_f32_16x16x32_bf16(af[i], bv[j], acc[i][j], 0, 0, 0);
        }
    }

    // epilogue
    float scale = 1.f;
    if (EPI == 1) {
        float e0 = __expf(alphap[0]);
        float e1 = __expf(alphap[1]);
        scale = ((m0 >= Asplit) ? e1 : e0) / (e0 + e1);
    }
    const int crow0 = m0 + wm + (lane >> 4) * 4;
    const int ccol0 = n0 + wn + l15;
#pragma unroll
    for (int i = 0; i < 4; ++i)
#pragma unroll
        for (int j = 0; j < 4; ++j)
#pragma unroll
            for (int q = 0; q < 4; ++q) {
                int gr = crow0 + i * 16 + q;
                int gc = ccol0 + j * 16;
                float v = acc[i][j][q];
                if (EPI == 1) v *= scale;
                if (EPI == 2) {
                    v = fmaxf(v, aux[(size_t)gr * N_COL + gc]);
                    v += bias[gc];
                    v = fmaxf(v, 0.f);
                }
                C[(size_t)gr * N_COL + gc] = v;
            }
}

extern "C" void kernel_launch(void* const* d_in, const int* in_sizes, int n_in,
                              void* d_out, int out_size, void* d_ws, size_t ws_size,
                              hipStream_t stream) {
    const float* x     = (const float*)d_in[0];
    const float* W     = (const float*)d_in[1];
    const float* alpha = (const float*)d_in[2];
    const float* bias  = (const float*)d_in[3];
    const float* s0    = (const float*)d_in[4];
    const float* s1    = (const float*)d_in[5];
    const float* s2    = (const float*)d_in[6];
    const float* s3    = (const float*)d_in[7];
    float* out = (float*)d_out;

    const int Nn = 8192, D = 512, Kf = 2048;
    float* pre  = (float*)d_ws;                       // [8192][512] f32
    float* tbuf = pre  + (size_t)Nn * D;              // [8192][512] f32 (t1 rows 0..2047, t3 rows 2048..)
    float* olow = tbuf + (size_t)Nn * D;              // [8192][512] f32

    dim3 blk(256);
    dim3 grd((Nn / 128) * NB);   // 256 blocks

    // 1) pre = x @ W            (M=8192, K=512)
    gemm_bf16_k<0><<<grd, blk, 0, stream>>>(x, x, 1 << 30, D, W, pre, Nn, D,
                                            nullptr, nullptr, nullptr);
    // 2) t = [s1; s3] @ pre, scaled by softmax(alpha)[row<2048 ? 0 : 1]   (K=8192)
    gemm_bf16_k<1><<<grd, blk, 0, stream>>>(s1, s3, Kf, Nn, pre, tbuf, Nn, Nn,
                                            alpha, nullptr, nullptr);
    // 3) olow = s0 @ t_low      (M=8192, K=2048)
    gemm_bf16_k<0><<<grd, blk, 0, stream>>>(s0, s0, 1 << 30, Kf, tbuf, olow, Nn, Kf,
                                            nullptr, nullptr, nullptr);
    // 4) out = relu(max(s2 @ t_high, olow) + bias)   (K=6144)
    gemm_bf16_k<2><<<grd, blk, 0, stream>>>(s2, s2, 1 << 30, Nn - Kf,
                                            tbuf + (size_t)Kf * D, out, Nn, Nn - Kf,
                                            nullptr, bias, olow);
}